// Round 5
// baseline (290.074 us; speedup 1.0000x reference)
//
#include <hip/hip_runtime.h>
#include <hip/hip_bf16.h>
#include <stdint.h>

// Problem constants (from reference): B=2, L=4096, H=1024
#define BB 2
#define LL 4096
#define HH 1024

typedef __bf16 bf16;
typedef __bf16 bf16x4 __attribute__((ext_vector_type(4)));
typedef __bf16 bf16x8 __attribute__((ext_vector_type(8)));
typedef float  f32x4  __attribute__((ext_vector_type(4)));

// ---------------------------------------------------------------------------
// RoPE: h[b,l,i] = x*cos + rotate_half(x)*sin, fp32 in -> bf16 out [B,L,H]
// ---------------------------------------------------------------------------
__global__ __launch_bounds__(128) void rope_kernel(
    const float* __restrict__ x, const float* __restrict__ cs,
    const float* __restrict__ sn, bf16* __restrict__ h)
{
    const int l = blockIdx.x;
    const int b = blockIdx.y;
    const int i = threadIdx.x * 4;            // 0..508
    const long xb = ((long)b * LL + l) * HH;
    const long cb = (long)l * HH;

    const float4 x1 = *(const float4*)(x + xb + i);
    const float4 x2 = *(const float4*)(x + xb + i + HH / 2);
    const float4 c1 = *(const float4*)(cs + cb + i);
    const float4 c2 = *(const float4*)(cs + cb + i + HH / 2);
    const float4 s1 = *(const float4*)(sn + cb + i);
    const float4 s2 = *(const float4*)(sn + cb + i + HH / 2);

    bf16x4 o1, o2;
    o1[0] = (bf16)(x1.x * c1.x - x2.x * s1.x);
    o1[1] = (bf16)(x1.y * c1.y - x2.y * s1.y);
    o1[2] = (bf16)(x1.z * c1.z - x2.z * s1.z);
    o1[3] = (bf16)(x1.w * c1.w - x2.w * s1.w);
    o2[0] = (bf16)(x2.x * c2.x + x1.x * s2.x);
    o2[1] = (bf16)(x2.y * c2.y + x1.y * s2.y);
    o2[2] = (bf16)(x2.z * c2.z + x1.z * s2.z);
    o2[3] = (bf16)(x2.w * c2.w + x1.w * s2.w);

    *(bf16x4*)(h + xb + i)          = o1;
    *(bf16x4*)(h + xb + i + HH / 2) = o2;
}

// ---------------------------------------------------------------------------
// bf16 transpose [R,C] -> [C,R], batched over z. 64x64 tiles, 256 threads.
// ---------------------------------------------------------------------------
__global__ __launch_bounds__(256) void transpose_bf16_64(
    const bf16* __restrict__ in, bf16* __restrict__ out, const int R, const int C)
{
    __shared__ uint32_t lds[64][36];
    const long zoff = (long)blockIdx.z * R * C;
    const int r0 = blockIdx.x * 64;
    const int c0 = blockIdx.y * 64;
    const int t  = threadIdx.x;

    const int c8 = t & 7;
    const int rr = t >> 3;                    // 0..31
    const bf16* p0 = in + zoff + (long)(r0 + 2 * rr) * C + c0 + c8 * 8;
    const uint4 ra = *(const uint4*)p0;
    const uint4 rb = *(const uint4*)(p0 + C);
    const uint32_t av[4] = {ra.x, ra.y, ra.z, ra.w};
    const uint32_t bv[4] = {rb.x, rb.y, rb.z, rb.w};
#pragma unroll
    for (int j = 0; j < 4; ++j) {
        const uint32_t alo = av[j] & 0xffffu, ahi = av[j] >> 16;
        const uint32_t blo = bv[j] & 0xffffu, bhi = bv[j] >> 16;
        lds[c8 * 8 + 2 * j    ][rr] = alo | (blo << 16);
        lds[c8 * 8 + 2 * j + 1][rr] = ahi | (bhi << 16);
    }
    __syncthreads();

    const int c = t >> 2;                     // 0..63
    const int q = t & 3;                      // 0..3
    const uint4 w0 = *(const uint4*)&lds[c][q * 8];
    const uint4 w1 = *(const uint4*)&lds[c][q * 8 + 4];
    bf16* po = out + zoff + (long)(c0 + c) * R + r0 + q * 16;
    *(uint4*)(po)     = w0;
    *(uint4*)(po + 8) = w1;
}

// ---------------------------------------------------------------------------
// W_q fp32 [H,H] -> Wt bf16 [H,H], Wt[i][o] = W_q[o][i]. 32x32 tiles.
// ---------------------------------------------------------------------------
__global__ __launch_bounds__(1024) void transpose_wq(
    const float* __restrict__ Wq, bf16* __restrict__ Wt)
{
    __shared__ float lds[32][33];
    const int r0 = blockIdx.x * 32;
    const int c0 = blockIdx.y * 32;
    const int tx = threadIdx.x, ty = threadIdx.y;
    lds[ty][tx] = Wq[(long)(r0 + ty) * HH + c0 + tx];
    __syncthreads();
    Wt[(long)(c0 + ty) * HH + r0 + tx] = (bf16)lds[tx][ty];
}

// ---------------------------------------------------------------------------
// R4 GEMM: C[m,n] = sum_k A[m,k]*B[n,k], 128x128 block tile, 4 waves (2x2 of
// 64x64), 16x16x32 bf16 MFMA — **no LDS, no barriers**. Both MFMA operands
// have layout [row=lane&15, k=(lane>>4)*8+j], which in [*,K] row-major
// storage is a contiguous 16-B segment per lane -> fragments load DIRECTLY
// from global (global_load_dwordx4), and a 2-stage register pipeline keeps
// the next tile's 8 loads in flight across the current tile's 16 MFMAs with
// compiler-issued fine-grained vmcnt(N) — no __syncthreads vmcnt(0) drain
// (the structural stall of the LDS version: m97/m131-m141).
// Cost: 2x intra-block fetch redundancy (waves don't share) — L1/L2-absorbed.
// ---------------------------------------------------------------------------
#define GEMM_PROLOGUE()                                                        \
    constexpr int BK = 32;                                                     \
    const int m0 = blockIdx.x * 128;                                           \
    const int n0 = blockIdx.y * 128;                                           \
    const int tid  = threadIdx.x;                                              \
    const int lane = tid & 63;                                                 \
    const int wave = tid >> 6;                                                 \
    const int wm = (wave & 1) * 64;                                            \
    const int wn = (wave >> 1) * 64;                                           \
    const int fr = lane & 15;                                                  \
    const int fq = lane >> 4;                                                  \
    const bf16* Ap = Ab + (long)(m0 + wm + fr) * K + fq * 8;                   \
    const bf16* Bp = Bb + (long)(n0 + wn + fr) * K + fq * 8;                   \
    const f32x4 vzero = {0.f, 0.f, 0.f, 0.f};                                  \
    f32x4 acc[4][4];                                                           \
    _Pragma("unroll") for (int i = 0; i < 4; ++i)                              \
        _Pragma("unroll") for (int j = 0; j < 4; ++j) acc[i][j] = vzero;

#define LOADFRAGS(AD, BD, KO)                                                  \
    do {                                                                       \
        _Pragma("unroll") for (int i = 0; i < 4; ++i)                          \
            AD[i] = *(const bf16x8*)(Ap + (long)i * 16 * K + (KO));            \
        _Pragma("unroll") for (int j = 0; j < 4; ++j)                          \
            BD[j] = *(const bf16x8*)(Bp + (long)j * 16 * K + (KO));            \
    } while (0)

#define MFMA_TILE(AF, BF)                                                      \
    _Pragma("unroll") for (int i = 0; i < 4; ++i)                              \
        _Pragma("unroll") for (int j = 0; j < 4; ++j)                          \
            acc[i][j] = __builtin_amdgcn_mfma_f32_16x16x32_bf16(               \
                AF[i], BF[j], acc[i][j], 0, 0, 0);

#define GEMM_KLOOP(KBASE, KEND)                                                \
    {                                                                          \
        bf16x8 a0[4], b0[4], a1[4], b1[4];                                     \
        LOADFRAGS(a0, b0, KBASE);                                              \
        int k0 = (KBASE);                                                      \
        for (; k0 + BK < (KEND); k0 += 2 * BK) {                               \
            LOADFRAGS(a1, b1, k0 + BK);                                        \
            MFMA_TILE(a0, b0);                                                 \
            if (k0 + 2 * BK < (KEND)) LOADFRAGS(a0, b0, k0 + 2 * BK);          \
            MFMA_TILE(a1, b1);                                                 \
        }                                                                      \
        if (k0 < (KEND)) MFMA_TILE(a0, b0);                                    \
    }

// epilogue C/D layout: col = lane&15, row = (lane>>4)*4 + reg [m89/m91]
#define GEMM_EPILOGUE(DST, DT)                                                 \
    _Pragma("unroll") for (int i = 0; i < 4; ++i) {                            \
        _Pragma("unroll") for (int r = 0; r < 4; ++r) {                        \
            const int row = m0 + wm + i * 16 + fq * 4 + r;                     \
            _Pragma("unroll") for (int j = 0; j < 4; ++j) {                    \
                const int col = n0 + wn + j * 16 + fr;                         \
                (DST)[(long)row * N + col] = (DT)acc[i][j][r];                 \
            }                                                                  \
        }                                                                      \
    }

// full-K GEMM, batched via blockIdx.z (sB=0 broadcasts B)
template <typename OUT_T>
__global__ __launch_bounds__(256) void gemm_bt(
    const bf16* __restrict__ A, const bf16* __restrict__ B, OUT_T* __restrict__ C,
    const int M, const int N, const int K,
    const long sA, const long sB, const long sC)
{
    const bf16* Ab = A + blockIdx.z * sA;
    const bf16* Bb = B + blockIdx.z * sB;
    OUT_T*      Cb = C + blockIdx.z * sC;
    GEMM_PROLOGUE();
    GEMM_KLOOP(0, K);
    GEMM_EPILOGUE(Cb, OUT_T);
}

// split-K GEMM: blockIdx.z = batch*S + split; fp32 partials P[z][M*N]
__global__ __launch_bounds__(256) void gemm_splitk(
    const bf16* __restrict__ A, const bf16* __restrict__ B, float* __restrict__ P,
    const int M, const int N, const int K, const int Ksplit, const int S,
    const long sA, const long sB)
{
    const int zb = blockIdx.z / S;
    const int zs = blockIdx.z % S;
    const bf16* Ab = A + zb * sA;
    const bf16* Bb = B + zb * sB;
    float* Pb = P + (long)blockIdx.z * M * N;
    const int kbase = zs * Ksplit;
    GEMM_PROLOGUE();
    GEMM_KLOOP(kbase, kbase + Ksplit);
    GEMM_EPILOGUE(Pb, float);
}

// sum S fp32 partial planes -> bf16. grid (npb/1024, B), block 256.
__global__ __launch_bounds__(256) void reduce_splits(
    const float* __restrict__ P, bf16* __restrict__ out, const int npb, const int S)
{
    const int b = blockIdx.y;
    const long r = ((long)blockIdx.x * 256 + threadIdx.x) * 4;
    const float* base = P + (long)b * S * npb + r;
    float4 a = *(const float4*)(base);
    for (int s = 1; s < S; ++s) {
        const float4 v = *(const float4*)(base + (long)s * npb);
        a.x += v.x; a.y += v.y; a.z += v.z; a.w += v.w;
    }
    bf16x4 o;
    o[0] = (bf16)a.x; o[1] = (bf16)a.y; o[2] = (bf16)a.z; o[3] = (bf16)a.w;
    *(bf16x4*)(out + (long)b * npb + r) = o;
}

// ---------------------------------------------------------------------------
// O = h @ (W_q^T @ (h^T h)) per batch  — associativity-reordered reference.
// Workspace (106 MB when split-K enabled):
//   h  bf16 [B,L,H]  @ 0      | hT bf16 [B,H,L] @ 16M | Wt bf16 [H,H] @ 32M
//   G  bf16 [B,H,H]  @ 34M    | Mt bf16 [B,H,H] @ 38M | P fp32 (64 MB) @ 42M
// ---------------------------------------------------------------------------
extern "C" void kernel_launch(void* const* d_in, const int* in_sizes, int n_in,
                              void* d_out, int out_size, void* d_ws, size_t ws_size,
                              hipStream_t stream)
{
    const float* x  = (const float*)d_in[0];   // hidden_states [B,L,H]
    const float* Wq = (const float*)d_in[1];   // [H,H]
    const float* cs = (const float*)d_in[2];   // [L,H]
    const float* sn = (const float*)d_in[3];   // [L,H]
    float* out = (float*)d_out;                // [B,L,H] fp32
    char* ws = (char*)d_ws;

    bf16*  h  = (bf16*)(ws);
    bf16*  hT = (bf16*)(ws + 16u * 1024 * 1024);
    bf16*  Wt = (bf16*)(ws + 32u * 1024 * 1024);
    bf16*  G  = (bf16*)(ws + 34u * 1024 * 1024);
    bf16*  Mt = (bf16*)(ws + 38u * 1024 * 1024);
    float* P  = (float*)(ws + 42u * 1024 * 1024);   // 16 planes of H*H fp32

    const bool big_ws = ws_size >= (size_t)106 * 1024 * 1024;

    // 1) RoPE -> bf16 h
    rope_kernel<<<dim3(LL, BB), 128, 0, stream>>>(x, cs, sn, h);

    // 2) h -> hT (per batch [L,H] -> [H,L]) so the G GEMM has K contiguous
    transpose_bf16_64<<<dim3(LL / 64, HH / 64, BB), 256, 0, stream>>>(h, hT, LL, HH);

    // 3) W_q -> Wt = W_q^T in bf16
    transpose_wq<<<dim3(HH / 32, HH / 32), dim3(32, 32), 0, stream>>>(Wq, Wt);

    if (big_ws) {
        // 4) G_b = hT_b @ hT_b^T, K=4096 split 8 ways -> 1024 blocks
        gemm_splitk<<<dim3(HH / 128, HH / 128, BB * 8), 256, 0, stream>>>(
            hT, hT, P, HH, HH, LL, LL / 8, 8, (long)HH * LL, (long)HH * LL);
        reduce_splits<<<dim3(HH * HH / 1024, BB), 256, 0, stream>>>(P, G, HH * HH, 8);

        // 5) Mt_b = G_b @ Wt^T, K=1024 split 4 ways -> 512 blocks
        gemm_splitk<<<dim3(HH / 128, HH / 128, BB * 4), 256, 0, stream>>>(
            G, Wt, P, HH, HH, HH, HH / 4, 4, (long)HH * HH, 0L);
        reduce_splits<<<dim3(HH * HH / 1024, BB), 256, 0, stream>>>(P, Mt, HH * HH, 4);
    } else {
        // fallback: unsplit (latency-bound but correct in 42 MB ws)
        gemm_bt<bf16><<<dim3(HH / 128, HH / 128, BB), 256, 0, stream>>>(
            hT, hT, G, HH, HH, LL, (long)HH * LL, (long)HH * LL, (long)HH * HH);
        gemm_bt<bf16><<<dim3(HH / 128, HH / 128, BB), 256, 0, stream>>>(
            G, Wt, Mt, HH, HH, HH, (long)HH * HH, 0L, (long)HH * HH);
    }

    // 6) O_b = h_b @ Mt_b^T : O[l,j] = sum_i h[l,i] Mt[j,i]  -> fp32 out
    gemm_bt<float><<<dim3(LL / 128, HH / 128, BB), 256, 0, stream>>>(
        h, Mt, out, LL, HH, HH, (long)LL * HH, (long)HH * HH, (long)LL * HH);
}

// Round 7
// 214.544 us; speedup vs baseline: 1.3521x; 1.3521x over previous
//
#include <hip/hip_runtime.h>
#include <hip/hip_bf16.h>
#include <stdint.h>

// Problem constants (from reference): B=2, L=4096, H=1024
#define BB 2
#define LL 4096
#define HH 1024

typedef __bf16 bf16;
typedef __bf16 bf16x4 __attribute__((ext_vector_type(4)));
typedef __bf16 bf16x8 __attribute__((ext_vector_type(8)));
typedef float  f32x4  __attribute__((ext_vector_type(4)));

// ---------------------------------------------------------------------------
// async global->LDS, 16 B per lane (m104/m108 semantics).
// ---------------------------------------------------------------------------
__device__ __forceinline__ void async_cp16(const bf16* g, const bf16* l)
{
    typedef const uint32_t __attribute__((address_space(1)))* gp_t;
    typedef uint32_t __attribute__((address_space(3)))* lp_t;
    __builtin_amdgcn_global_load_lds((gp_t)(uintptr_t)g, (lp_t)(uintptr_t)l, 16, 0, 0);
}

// ---------------------------------------------------------------------------
// RoPE: h[b,l,i] = x*cos + rotate_half(x)*sin, fp32 in -> bf16 out [B,L,H]
// (R2-proven version — the R5 fused rope+transpose is quarantined.)
// ---------------------------------------------------------------------------
__global__ __launch_bounds__(128) void rope_kernel(
    const float* __restrict__ x, const float* __restrict__ cs,
    const float* __restrict__ sn, bf16* __restrict__ h)
{
    const int l = blockIdx.x;
    const int b = blockIdx.y;
    const int i = threadIdx.x * 4;            // 0..508
    const long xb = ((long)b * LL + l) * HH;
    const long cb = (long)l * HH;

    const float4 x1 = *(const float4*)(x + xb + i);
    const float4 x2 = *(const float4*)(x + xb + i + HH / 2);
    const float4 c1 = *(const float4*)(cs + cb + i);
    const float4 c2 = *(const float4*)(cs + cb + i + HH / 2);
    const float4 s1 = *(const float4*)(sn + cb + i);
    const float4 s2 = *(const float4*)(sn + cb + i + HH / 2);

    bf16x4 o1, o2;
    o1[0] = (bf16)(x1.x * c1.x - x2.x * s1.x);
    o1[1] = (bf16)(x1.y * c1.y - x2.y * s1.y);
    o1[2] = (bf16)(x1.z * c1.z - x2.z * s1.z);
    o1[3] = (bf16)(x1.w * c1.w - x2.w * s1.w);
    o2[0] = (bf16)(x2.x * c2.x + x1.x * s2.x);
    o2[1] = (bf16)(x2.y * c2.y + x1.y * s2.y);
    o2[2] = (bf16)(x2.z * c2.z + x1.z * s2.z);
    o2[3] = (bf16)(x2.w * c2.w + x1.w * s2.w);

    *(bf16x4*)(h + xb + i)          = o1;
    *(bf16x4*)(h + xb + i + HH / 2) = o2;
}

// ---------------------------------------------------------------------------
// bf16 transpose [R,C] -> [C,R], batched over z. 64x64 tiles, 256 threads.
// (R1-fixed, R2/R3/R4-proven.)
// ---------------------------------------------------------------------------
__global__ __launch_bounds__(256) void transpose_bf16_64(
    const bf16* __restrict__ in, bf16* __restrict__ out, const int R, const int C)
{
    __shared__ uint32_t lds[64][36];
    const long zoff = (long)blockIdx.z * R * C;
    const int r0 = blockIdx.x * 64;
    const int c0 = blockIdx.y * 64;
    const int t  = threadIdx.x;

    const int c8 = t & 7;
    const int rr = t >> 3;                    // 0..31
    const bf16* p0 = in + zoff + (long)(r0 + 2 * rr) * C + c0 + c8 * 8;
    const uint4 ra = *(const uint4*)p0;
    const uint4 rb = *(const uint4*)(p0 + C);
    const uint32_t av[4] = {ra.x, ra.y, ra.z, ra.w};
    const uint32_t bv[4] = {rb.x, rb.y, rb.z, rb.w};
#pragma unroll
    for (int j = 0; j < 4; ++j) {
        const uint32_t alo = av[j] & 0xffffu, ahi = av[j] >> 16;
        const uint32_t blo = bv[j] & 0xffffu, bhi = bv[j] >> 16;
        lds[c8 * 8 + 2 * j    ][rr] = alo | (blo << 16);
        lds[c8 * 8 + 2 * j + 1][rr] = ahi | (bhi << 16);
    }
    __syncthreads();

    const int c = t >> 2;                     // 0..63
    const int q = t & 3;                      // 0..3
    const uint4 w0 = *(const uint4*)&lds[c][q * 8];
    const uint4 w1 = *(const uint4*)&lds[c][q * 8 + 4];
    bf16* po = out + zoff + (long)(c0 + c) * R + r0 + q * 16;
    *(uint4*)(po)     = w0;
    *(uint4*)(po + 8) = w1;
}

// ---------------------------------------------------------------------------
// W_q fp32 -> bf16 elementwise (no transpose: q-GEMM reads Wq as [N=o,K=i],
// K contiguous). grid n/1024, 256 thr.
// ---------------------------------------------------------------------------
__global__ __launch_bounds__(256) void cast_wq(
    const float* __restrict__ Wq, bf16* __restrict__ Wb)
{
    const long idx = ((long)blockIdx.x * 256 + threadIdx.x) * 4;
    const float4 v = *(const float4*)(Wq + idx);
    bf16x4 o;
    o[0] = (bf16)v.x; o[1] = (bf16)v.y; o[2] = (bf16)v.z; o[3] = (bf16)v.w;
    *(bf16x4*)(Wb + idx) = o;
}

// ---------------------------------------------------------------------------
// GEMM core (R3 structure — best measured): C[m,n] = sum_k A[m,k]*B[n,k],
// 128x128 tile, BK=32, 4 waves (2x2 of 64x64), 16x16x32 bf16 MFMA,
// double-buffered LDS with depth-1 global_load_lds prefetch.
// ---------------------------------------------------------------------------
#define GEMM_PROLOGUE()                                                        \
    constexpr int BK = 32;                                                     \
    __shared__ __align__(16) bf16 As[2][128][32];                              \
    __shared__ __align__(16) bf16 Bs[2][128][32];                              \
    const int m0 = blockIdx.x * 128;                                           \
    const int n0 = blockIdx.y * 128;                                           \
    const int tid  = threadIdx.x;                                              \
    const int lane = tid & 63;                                                 \
    const int wave = tid >> 6;                                                 \
    const int wm = (wave & 1) * 64;                                            \
    const int wn = (wave >> 1) * 64;                                           \
    const int fr = lane & 15;                                                  \
    const int fq = lane >> 4;                                                  \
    const int srow = tid >> 2;                                                 \
    const int scol = (tid & 3) * 8;                                            \
    const int woff0 = wave * 512;          /* pass0: rows 0..63  */            \
    const int woff1 = 2048 + wave * 512;   /* pass1: rows 64..127*/            \
    const bf16* Ag = Ab + (long)(m0 + srow) * K + scol;                        \
    const bf16* Bg = Bb + (long)(n0 + srow) * K + scol;                        \
    const f32x4 vzero = {0.f, 0.f, 0.f, 0.f};                                  \
    f32x4 acc[4][4];                                                           \
    _Pragma("unroll") for (int i = 0; i < 4; ++i)                              \
        _Pragma("unroll") for (int j = 0; j < 4; ++j) acc[i][j] = vzero;

#define GEMM_PREFETCH(KOFF, BUF)                                               \
    do {                                                                       \
        async_cp16(Ag + (KOFF),           &As[BUF][0][0] + woff0);             \
        async_cp16(Ag + (KOFF) + 64L * K, &As[BUF][0][0] + woff1);             \
        async_cp16(Bg + (KOFF),           &Bs[BUF][0][0] + woff0);             \
        async_cp16(Bg + (KOFF) + 64L * K, &Bs[BUF][0][0] + woff1);             \
    } while (0)

#define GEMM_KLOOP(KBASE, KEND)                                                \
    {                                                                          \
        GEMM_PREFETCH(KBASE, 0);                                               \
        int buf = 0;                                                           \
        for (int k0 = (KBASE); k0 < (KEND); k0 += BK, buf ^= 1) {              \
            __syncthreads();               /* tile(buf) resident in LDS */     \
            if (k0 + BK < (KEND)) GEMM_PREFETCH(k0 + BK, buf ^ 1);             \
            bf16x8 af[4], bfv[4];                                              \
            _Pragma("unroll") for (int i = 0; i < 4; ++i)                      \
                af[i]  = *(const bf16x8*)&As[buf][wm + i * 16 + fr][fq * 8];   \
            _Pragma("unroll") for (int j = 0; j < 4; ++j)                      \
                bfv[j] = *(const bf16x8*)&Bs[buf][wn + j * 16 + fr][fq * 8];   \
            _Pragma("unroll") for (int i = 0; i < 4; ++i)                      \
                _Pragma("unroll") for (int j = 0; j < 4; ++j)                  \
                    acc[i][j] = __builtin_amdgcn_mfma_f32_16x16x32_bf16(       \
                        af[i], bfv[j], acc[i][j], 0, 0, 0);                    \
        }                                                                      \
    }

// epilogue C/D layout: col = lane&15, row = (lane>>4)*4 + reg [m89/m91]
#define GEMM_EPILOGUE(DST, DT)                                                 \
    _Pragma("unroll") for (int i = 0; i < 4; ++i) {                            \
        _Pragma("unroll") for (int r = 0; r < 4; ++r) {                        \
            const int row = m0 + wm + i * 16 + fq * 4 + r;                     \
            _Pragma("unroll") for (int j = 0; j < 4; ++j) {                    \
                const int col = n0 + wn + j * 16 + fr;                         \
                (DST)[(long)row * N + col] = (DT)acc[i][j][r];                 \
            }                                                                  \
        }                                                                      \
    }

// full-K GEMM, batched via blockIdx.z (sB=0 broadcasts B)
template <typename OUT_T>
__global__ __launch_bounds__(256) void gemm_bt(
    const bf16* __restrict__ A, const bf16* __restrict__ B, OUT_T* __restrict__ C,
    const int M, const int N, const int K,
    const long sA, const long sB, const long sC)
{
    const bf16* Ab = A + blockIdx.z * sA;
    const bf16* Bb = B + blockIdx.z * sB;
    OUT_T*      Cb = C + blockIdx.z * sC;
    GEMM_PROLOGUE();
    GEMM_KLOOP(0, K);
    GEMM_EPILOGUE(Cb, OUT_T);
}

// split-K GEMM: blockIdx.z = batch*S + split; fp32 partials P[z][M*N]
__global__ __launch_bounds__(256) void gemm_splitk(
    const bf16* __restrict__ A, const bf16* __restrict__ B, float* __restrict__ P,
    const int M, const int N, const int K, const int Ksplit, const int S,
    const long sA, const long sB)
{
    const int zb = blockIdx.z / S;
    const int zs = blockIdx.z % S;
    const bf16* Ab = A + zb * sA;
    const bf16* Bb = B + zb * sB;
    float* Pb = P + (long)blockIdx.z * M * N;
    const int kbase = zs * Ksplit;
    GEMM_PROLOGUE();
    GEMM_KLOOP(kbase, kbase + Ksplit);
    GEMM_EPILOGUE(Pb, float);
}

// sum S fp32 partial planes -> bf16. grid (npb/1024, B), block 256.
__global__ __launch_bounds__(256) void reduce_splits(
    const float* __restrict__ P, bf16* __restrict__ out, const int npb, const int S)
{
    const int b = blockIdx.y;
    const long r = ((long)blockIdx.x * 256 + threadIdx.x) * 4;
    const float* base = P + (long)b * S * npb + r;
    float4 a = *(const float4*)(base);
    for (int s = 1; s < S; ++s) {
        const float4 v = *(const float4*)(base + (long)s * npb);
        a.x += v.x; a.y += v.y; a.z += v.z; a.w += v.w;
    }
    bf16x4 o;
    o[0] = (bf16)a.x; o[1] = (bf16)a.y; o[2] = (bf16)a.z; o[3] = (bf16)a.w;
    *(bf16x4*)(out + (long)b * npb + r) = o;
}

// ---------------------------------------------------------------------------
// R6 pipeline (proven preprocessing + q·G re-association, no M GEMM):
//   h = RoPE(x); hT = h^T; G_b = hT_b·hT_b^T (split-K S=8);
//   q_b = h_b·Wq^T; O_b = q_b·G_b (G symmetric -> A·B^T form exact).
// Workspace (102 MB; R3/R4 proved ws >= 106 MB runs split-K):
//   h@0 (16M) | hT@16M (16M) | Wb@32M (2M) | G@34M (4M) | P@38M (64M, S=8)
//   q aliases P's first 16 MB — P is dead after reduce_splits (stream order).
// ---------------------------------------------------------------------------
extern "C" void kernel_launch(void* const* d_in, const int* in_sizes, int n_in,
                              void* d_out, int out_size, void* d_ws, size_t ws_size,
                              hipStream_t stream)
{
    const float* x  = (const float*)d_in[0];   // hidden_states [B,L,H]
    const float* Wq = (const float*)d_in[1];   // [H,H]
    const float* cs = (const float*)d_in[2];   // [L,H]
    const float* sn = (const float*)d_in[3];   // [L,H]
    float* out = (float*)d_out;                // [B,L,H] fp32
    char* ws = (char*)d_ws;

    bf16*  h  = (bf16*)(ws);
    bf16*  hT = (bf16*)(ws + 16u * 1024 * 1024);
    bf16*  Wb = (bf16*)(ws + 32u * 1024 * 1024);
    bf16*  G  = (bf16*)(ws + 34u * 1024 * 1024);
    float* P  = (float*)(ws + 38u * 1024 * 1024);   // 16 planes of H*H fp32

    const bool big_ws = ws_size >= (size_t)102 * 1024 * 1024;
    bf16* q = big_ws ? (bf16*)P : (bf16*)(ws + 38u * 1024 * 1024); // alias: P dead before q written

    // 1) RoPE -> bf16 h  (R2-proven)
    rope_kernel<<<dim3(LL, BB), 128, 0, stream>>>(x, cs, sn, h);

    // 2) h -> hT per batch  (R2-proven)
    transpose_bf16_64<<<dim3(LL / 64, HH / 64, BB), 256, 0, stream>>>(h, hT, LL, HH);

    // 3) Wq -> bf16
    cast_wq<<<dim3(HH * HH / 1024), 256, 0, stream>>>(Wq, Wb);

    // 4) G_b = hT_b @ hT_b^T  (K=4096)
    if (big_ws) {
        gemm_splitk<<<dim3(HH / 128, HH / 128, BB * 8), 256, 0, stream>>>(
            hT, hT, P, HH, HH, LL, LL / 8, 8, (long)HH * LL, (long)HH * LL);
        reduce_splits<<<dim3(HH * HH / 1024, BB), 256, 0, stream>>>(P, G, HH * HH, 8);
    } else {
        gemm_bt<bf16><<<dim3(HH / 128, HH / 128, BB), 256, 0, stream>>>(
            hT, hT, G, HH, HH, LL, (long)HH * LL, (long)HH * LL, (long)HH * HH);
    }

    // 5) q_b = h_b @ Wq^T : q[l,o] = sum_i h[l,i] Wq[o,i]  (Wq as [N=o,K=i])
    gemm_bt<bf16><<<dim3(LL / 128, HH / 128, BB), 256, 0, stream>>>(
        h, Wb, q, LL, HH, HH, (long)LL * HH, 0L, (long)LL * HH);

    // 6) O_b = q_b @ G_b : O[l,j] = sum_i q[l,i] G[j,i]  (G symmetric)
    gemm_bt<float><<<dim3(LL / 128, HH / 128, BB), 256, 0, stream>>>(
        q, G, out, LL, HH, HH, (long)LL * HH, (long)HH * HH, (long)LL * HH);
}

// Round 8
// 194.431 us; speedup vs baseline: 1.4919x; 1.1034x over previous
//
#include <hip/hip_runtime.h>
#include <hip/hip_bf16.h>
#include <stdint.h>

// Problem constants (from reference): B=2, L=4096, H=1024
#define BB 2
#define LL 4096
#define HH 1024
#define GBK 32   // GEMM K-tile

typedef __bf16 bf16;
typedef __bf16 bf16x4 __attribute__((ext_vector_type(4)));
typedef __bf16 bf16x8 __attribute__((ext_vector_type(8)));
typedef float  f32x4  __attribute__((ext_vector_type(4)));

// ---------------------------------------------------------------------------
// async global->LDS, 16 B per lane (m104/m108 semantics).
// ---------------------------------------------------------------------------
__device__ __forceinline__ void async_cp16(const bf16* g, const bf16* l)
{
    typedef const uint32_t __attribute__((address_space(1)))* gp_t;
    typedef uint32_t __attribute__((address_space(3)))* lp_t;
    __builtin_amdgcn_global_load_lds((gp_t)(uintptr_t)g, (lp_t)(uintptr_t)l, 16, 0, 0);
}

// ---------------------------------------------------------------------------
// RoPE: h[b,l,i] = x*cos + rotate_half(x)*sin, fp32 in -> bf16 out [B,L,H]
// (R2-proven.)
// ---------------------------------------------------------------------------
__global__ __launch_bounds__(128) void rope_kernel(
    const float* __restrict__ x, const float* __restrict__ cs,
    const float* __restrict__ sn, bf16* __restrict__ h)
{
    const int l = blockIdx.x;
    const int b = blockIdx.y;
    const int i = threadIdx.x * 4;            // 0..508
    const long xb = ((long)b * LL + l) * HH;
    const long cb = (long)l * HH;

    const float4 x1 = *(const float4*)(x + xb + i);
    const float4 x2 = *(const float4*)(x + xb + i + HH / 2);
    const float4 c1 = *(const float4*)(cs + cb + i);
    const float4 c2 = *(const float4*)(cs + cb + i + HH / 2);
    const float4 s1 = *(const float4*)(sn + cb + i);
    const float4 s2 = *(const float4*)(sn + cb + i + HH / 2);

    bf16x4 o1, o2;
    o1[0] = (bf16)(x1.x * c1.x - x2.x * s1.x);
    o1[1] = (bf16)(x1.y * c1.y - x2.y * s1.y);
    o1[2] = (bf16)(x1.z * c1.z - x2.z * s1.z);
    o1[3] = (bf16)(x1.w * c1.w - x2.w * s1.w);
    o2[0] = (bf16)(x2.x * c2.x + x1.x * s2.x);
    o2[1] = (bf16)(x2.y * c2.y + x1.y * s2.y);
    o2[2] = (bf16)(x2.z * c2.z + x1.z * s2.z);
    o2[3] = (bf16)(x2.w * c2.w + x1.w * s2.w);

    *(bf16x4*)(h + xb + i)          = o1;
    *(bf16x4*)(h + xb + i + HH / 2) = o2;
}

// ---------------------------------------------------------------------------
// bf16 transpose [R,C] -> [C,R], batched over z. 64x64 tiles, 256 threads.
// (R1-fixed, proven.)
// ---------------------------------------------------------------------------
__global__ __launch_bounds__(256) void transpose_bf16_64(
    const bf16* __restrict__ in, bf16* __restrict__ out, const int R, const int C)
{
    __shared__ uint32_t lds[64][36];
    const long zoff = (long)blockIdx.z * R * C;
    const int r0 = blockIdx.x * 64;
    const int c0 = blockIdx.y * 64;
    const int t  = threadIdx.x;

    const int c8 = t & 7;
    const int rr = t >> 3;                    // 0..31
    const bf16* p0 = in + zoff + (long)(r0 + 2 * rr) * C + c0 + c8 * 8;
    const uint4 ra = *(const uint4*)p0;
    const uint4 rb = *(const uint4*)(p0 + C);
    const uint32_t av[4] = {ra.x, ra.y, ra.z, ra.w};
    const uint32_t bv[4] = {rb.x, rb.y, rb.z, rb.w};
#pragma unroll
    for (int j = 0; j < 4; ++j) {
        const uint32_t alo = av[j] & 0xffffu, ahi = av[j] >> 16;
        const uint32_t blo = bv[j] & 0xffffu, bhi = bv[j] >> 16;
        lds[c8 * 8 + 2 * j    ][rr] = alo | (blo << 16);
        lds[c8 * 8 + 2 * j + 1][rr] = ahi | (bhi << 16);
    }
    __syncthreads();

    const int c = t >> 2;                     // 0..63
    const int q = t & 3;                      // 0..3
    const uint4 w0 = *(const uint4*)&lds[c][q * 8];
    const uint4 w1 = *(const uint4*)&lds[c][q * 8 + 4];
    bf16* po = out + zoff + (long)(c0 + c) * R + r0 + q * 16;
    *(uint4*)(po)     = w0;
    *(uint4*)(po + 8) = w1;
}

// ---------------------------------------------------------------------------
// W_q fp32 -> bf16 elementwise. grid n/1024, 256 thr.
// ---------------------------------------------------------------------------
__global__ __launch_bounds__(256) void cast_wq(
    const float* __restrict__ Wq, bf16* __restrict__ Wb)
{
    const long idx = ((long)blockIdx.x * 256 + threadIdx.x) * 4;
    const float4 v = *(const float4*)(Wq + idx);
    bf16x4 o;
    o[0] = (bf16)v.x; o[1] = (bf16)v.y; o[2] = (bf16)v.z; o[3] = (bf16)v.w;
    *(bf16x4*)(Wb + idx) = o;
}

// ---------------------------------------------------------------------------
// GEMM core macros (R3/R4-proven structure, parameterized): C[m,n] =
// sum_k A[m,k]*B[n,k]; 128x128 tile, BK=32, 4 waves (2x2 of 64x64),
// 16x16x32 bf16 MFMA, double-buffered LDS + depth-1 global_load_lds prefetch.
// Requires locals: Ab, Bb (bf16*), K (int). GEMM_SHARED() once per kernel.
// ---------------------------------------------------------------------------
#define GEMM_SHARED()                                                          \
    __shared__ __align__(16) bf16 As[2][128][32];                              \
    __shared__ __align__(16) bf16 Bs[2][128][32];

#define GEMM_PREFETCH(KOFF, BUF)                                               \
    do {                                                                       \
        async_cp16(Ag + (KOFF),           &As[BUF][0][0] + woff0);             \
        async_cp16(Ag + (KOFF) + 64L * K, &As[BUF][0][0] + woff1);             \
        async_cp16(Bg + (KOFF),           &Bs[BUF][0][0] + woff0);             \
        async_cp16(Bg + (KOFF) + 64L * K, &Bs[BUF][0][0] + woff1);             \
    } while (0)

#define GEMM_BODY(M0, N0, KBASE, KEND, DST, DT, LDN)                           \
    {                                                                          \
        const int tid  = threadIdx.x;                                          \
        const int lane = tid & 63;                                             \
        const int wave = tid >> 6;                                             \
        const int wm = (wave & 1) * 64;                                        \
        const int wn = (wave >> 1) * 64;                                       \
        const int fr = lane & 15;                                              \
        const int fq = lane >> 4;                                              \
        const int srow = tid >> 2;                                             \
        const int scol = (tid & 3) * 8;                                        \
        const int woff0 = wave * 512;          /* pass0: rows 0..63  */        \
        const int woff1 = 2048 + wave * 512;   /* pass1: rows 64..127*/        \
        const bf16* Ag = Ab + (long)((M0) + srow) * K + scol;                  \
        const bf16* Bg = Bb + (long)((N0) + srow) * K + scol;                  \
        const f32x4 vzero = {0.f, 0.f, 0.f, 0.f};                              \
        f32x4 acc[4][4];                                                       \
        _Pragma("unroll") for (int i = 0; i < 4; ++i)                          \
            _Pragma("unroll") for (int j = 0; j < 4; ++j) acc[i][j] = vzero;   \
        GEMM_PREFETCH(KBASE, 0);                                               \
        int buf = 0;                                                           \
        for (int k0 = (KBASE); k0 < (KEND); k0 += GBK, buf ^= 1) {             \
            __syncthreads();               /* tile(buf) resident in LDS */     \
            if (k0 + GBK < (KEND)) GEMM_PREFETCH(k0 + GBK, buf ^ 1);           \
            bf16x8 af[4], bfv[4];                                              \
            _Pragma("unroll") for (int i = 0; i < 4; ++i)                      \
                af[i]  = *(const bf16x8*)&As[buf][wm + i * 16 + fr][fq * 8];   \
            _Pragma("unroll") for (int j = 0; j < 4; ++j)                      \
                bfv[j] = *(const bf16x8*)&Bs[buf][wn + j * 16 + fr][fq * 8];   \
            _Pragma("unroll") for (int i = 0; i < 4; ++i)                      \
                _Pragma("unroll") for (int j = 0; j < 4; ++j)                  \
                    acc[i][j] = __builtin_amdgcn_mfma_f32_16x16x32_bf16(       \
                        af[i], bfv[j], acc[i][j], 0, 0, 0);                    \
        }                                                                      \
        /* C/D layout: col = lane&15, row = (lane>>4)*4 + reg [m89/m91] */     \
        _Pragma("unroll") for (int i = 0; i < 4; ++i) {                        \
            _Pragma("unroll") for (int r = 0; r < 4; ++r) {                    \
                const int row = (M0) + wm + i * 16 + fq * 4 + r;               \
                _Pragma("unroll") for (int j = 0; j < 4; ++j) {                \
                    const int col = (N0) + wn + j * 16 + fr;                   \
                    (DST)[(long)row * (LDN) + col] = (DT)acc[i][j][r];         \
                }                                                              \
            }                                                                  \
        }                                                                      \
    }

// full-K GEMM, batched via blockIdx.z (sB=0 broadcasts B)
template <typename OUT_T>
__global__ __launch_bounds__(256) void gemm_bt(
    const bf16* __restrict__ A, const bf16* __restrict__ B, OUT_T* __restrict__ C,
    const int M, const int N, const int K,
    const long sA, const long sB, const long sC)
{
    GEMM_SHARED();
    const bf16* Ab = A + blockIdx.z * sA;
    const bf16* Bb = B + blockIdx.z * sB;
    OUT_T*      Cb = C + blockIdx.z * sC;
    const int m0 = blockIdx.x * 128;
    const int n0 = blockIdx.y * 128;
    GEMM_BODY(m0, n0, 0, K, Cb, OUT_T, N);
}

// ---------------------------------------------------------------------------
// R7 merged kernel, flat 1D grid of 1024 blocks:
//  id in [0,512):  G split-K role. plane = id>>6 = zb*4+zs (S=4), tile=id&63
//                  (8x8). P[plane] += hT_zb[m-tile] · hT_zb[n-tile]^T over
//                  K-slab zs*1024..+1024.
//  id in [512,1024): q role. q = h·Wq^T with batch folded into M=8192.
// The two roles are independent (q reads h/Wb; G reads hT) -> co-scheduling
// fills 256 CUs at 4 blocks/CU instead of running 2 half-empty launches.
// ---------------------------------------------------------------------------
__global__ __launch_bounds__(256) void gemm_Gq(
    const bf16* __restrict__ hT, const bf16* __restrict__ Wb,
    const bf16* __restrict__ h, float* __restrict__ P, bf16* __restrict__ q)
{
    GEMM_SHARED();
    const int id = blockIdx.x;
    if (id < 512) {
        const int plane = id >> 6;            // zb*4 + zs
        const int zb = plane >> 2;
        const int zs = plane & 3;
        const int t  = id & 63;
        const int m0 = (t & 7) * 128;
        const int n0 = (t >> 3) * 128;
        const bf16* Ab = hT + (long)zb * HH * LL;
        const bf16* Bb = Ab;
        float* Cb = P + (long)plane * HH * HH;
        const int K = LL;
        const int kbase = zs * (LL / 4);
        GEMM_BODY(m0, n0, kbase, kbase + LL / 4, Cb, float, HH);
    } else {
        const int t  = id - 512;              // 0..511
        const int m0 = (t & 63) * 128;        // M = B*L = 8192
        const int n0 = (t >> 6) * 128;        // N = 1024
        const bf16* Ab = h;                   // [8192,1024] flat
        const bf16* Bb = Wb;
        const int K = HH;
        GEMM_BODY(m0, n0, 0, HH, q, bf16, HH);
    }
}

// sum S fp32 partial planes -> bf16. grid (npb/1024, B), block 256.
__global__ __launch_bounds__(256) void reduce_splits(
    const float* __restrict__ P, bf16* __restrict__ out, const int npb, const int S)
{
    const int b = blockIdx.y;
    const long r = ((long)blockIdx.x * 256 + threadIdx.x) * 4;
    const float* base = P + (long)b * S * npb + r;
    float4 a = *(const float4*)(base);
    for (int s = 1; s < S; ++s) {
        const float4 v = *(const float4*)(base + (long)s * npb);
        a.x += v.x; a.y += v.y; a.z += v.z; a.w += v.w;
    }
    bf16x4 o;
    o[0] = (bf16)a.x; o[1] = (bf16)a.y; o[2] = (bf16)a.z; o[3] = (bf16)a.w;
    *(bf16x4*)(out + (long)b * npb + r) = o;
}

// ---------------------------------------------------------------------------
// R7 pipeline: h = RoPE(x); hT = h^T; Wb = bf16(Wq);
//   [merged] G-partials (split-K S=4) + q = h·Wq^T;  G = reduce(P);
//   O_b = q_b · G_b  (G symmetric -> A·B^T exact).
// Workspace (86 MB used; harness provides ~256 MB):
//   h@0 (16M) | hT@16M (16M) | Wb@32M (2M) | G@34M (4M)
//   P@38M (8 planes fp32, 32M) | q@70M (16M)
// ---------------------------------------------------------------------------
extern "C" void kernel_launch(void* const* d_in, const int* in_sizes, int n_in,
                              void* d_out, int out_size, void* d_ws, size_t ws_size,
                              hipStream_t stream)
{
    const float* x  = (const float*)d_in[0];   // hidden_states [B,L,H]
    const float* Wq = (const float*)d_in[1];   // [H,H]
    const float* cs = (const float*)d_in[2];   // [L,H]
    const float* sn = (const float*)d_in[3];   // [L,H]
    float* out = (float*)d_out;                // [B,L,H] fp32
    char* ws = (char*)d_ws;

    bf16*  h  = (bf16*)(ws);
    bf16*  hT = (bf16*)(ws + 16u * 1024 * 1024);
    bf16*  Wb = (bf16*)(ws + 32u * 1024 * 1024);
    bf16*  G  = (bf16*)(ws + 34u * 1024 * 1024);
    float* P  = (float*)(ws + 38u * 1024 * 1024);   // 8 planes of H*H fp32

    const bool big_ws = ws_size >= (size_t)90 * 1024 * 1024;
    bf16* q = big_ws ? (bf16*)(ws + 70u * 1024 * 1024)
                     : (bf16*)(ws + 38u * 1024 * 1024);  // fallback: reuse P slot

    // 1) RoPE -> bf16 h
    rope_kernel<<<dim3(LL, BB), 128, 0, stream>>>(x, cs, sn, h);

    // 2) h -> hT per batch
    transpose_bf16_64<<<dim3(LL / 64, HH / 64, BB), 256, 0, stream>>>(h, hT, LL, HH);

    // 3) Wq -> bf16
    cast_wq<<<dim3(HH * HH / 1024), 256, 0, stream>>>(Wq, Wb);

    if (big_ws) {
        // 4) merged: G split-K partials + q GEMM, 1024 blocks
        gemm_Gq<<<dim3(1024), 256, 0, stream>>>(hT, Wb, h, P, q);
        // 5) G = sum of 4 planes per batch
        reduce_splits<<<dim3(HH * HH / 1024, BB), 256, 0, stream>>>(P, G, HH * HH, 4);
    } else {
        gemm_bt<bf16><<<dim3(HH / 128, HH / 128, BB), 256, 0, stream>>>(
            hT, hT, G, HH, HH, LL, (long)HH * LL, (long)HH * LL, (long)HH * HH);
        gemm_bt<bf16><<<dim3(LL / 128, HH / 128, BB), 256, 0, stream>>>(
            h, Wb, q, LL, HH, HH, (long)LL * HH, 0L, (long)LL * HH);
    }

    // 6) O_b = q_b @ G_b : O[l,j] = sum_i q[l,i] G[j,i]  (G symmetric)
    gemm_bt<float><<<dim3(LL / 128, HH / 128, BB), 256, 0, stream>>>(
        q, G, out, LL, HH, HH, (long)LL * HH, (long)HH * HH, (long)LL * HH);
}